// Round 8
// baseline (1104.126 us; speedup 1.0000x reference)
//
#include <hip/hip_runtime.h>
#include <hip/hip_bf16.h>

#define B_ROWS   524288
#define MEL_BINS 128
#define DIM      64
#define KCODES   128
#define THREADS  128

typedef float v2f __attribute__((ext_vector_type(2)));
typedef float v4f __attribute__((ext_vector_type(4)));

// packed fp32 FMA: two independent IEEE f32 FMAs per instruction.
// C (codebook/weight pair) is the single SGPR operand; Z duplicated scalar.
#define PK(A, C, Z) asm("v_pk_fma_f32 %0, %1, %2, %0" : "+v"(A) : "s"(C), "v"(Z))

// ---------------- workspace layout (floats) ----------------
#define WS_WT  0                            // 8192  : W_in^T, WT[j*64+d]
#define WS_C0T (WS_WT + MEL_BINS*DIM)       // 8192  : cb0^T, c0T[d*128+k]
#define WS_C1T (WS_C0T + DIM*KCODES)        // 8192  : cb1^T
#define WS_N0  (WS_C1T + DIM*KCODES)        // 128
#define WS_N1  (WS_N0 + KCODES)             // 128
#define WS_T0  (WS_N1 + KCODES)             // 16384 : cb0 @ W_out^T
#define WS_T1  (WS_T0 + KCODES*MEL_BINS)    // 16384
#define WS_TOT (WS_T1 + KCODES*MEL_BINS)    // 57600 floats

__device__ __forceinline__ float np_pairwise64_sq(const float* v) {
#pragma clang fp contract(off)
    float r0 = v[0]*v[0], r1 = v[1]*v[1], r2 = v[2]*v[2], r3 = v[3]*v[3];
    float r4 = v[4]*v[4], r5 = v[5]*v[5], r6 = v[6]*v[6], r7 = v[7]*v[7];
#pragma unroll
    for (int i = 8; i < 64; i += 8) {
        r0 += v[i+0]*v[i+0]; r1 += v[i+1]*v[i+1];
        r2 += v[i+2]*v[i+2]; r3 += v[i+3]*v[i+3];
        r4 += v[i+4]*v[i+4]; r5 += v[i+5]*v[i+5];
        r6 += v[i+6]*v[i+6]; r7 += v[i+7]*v[i+7];
    }
    return ((r0 + r1) + (r2 + r3)) + ((r4 + r5) + (r6 + r7));
}

__global__ __launch_bounds__(256) void rvq_precomp(
    const float* __restrict__ W_in, const float* __restrict__ cb0,
    const float* __restrict__ cb1, const float* __restrict__ W_out,
    float* __restrict__ ws)
{
#pragma clang fp contract(off)
    float* WT  = ws + WS_WT;
    float* c0T = ws + WS_C0T;
    float* c1T = ws + WS_C1T;
    float* n0  = ws + WS_N0;
    float* n1  = ws + WS_N1;
    float* T0  = ws + WS_T0;
    float* T1  = ws + WS_T1;

    int tid = blockIdx.x * 256 + threadIdx.x;
    if (tid < 16384) {
        int i = tid >> 7, m = tid & 127;
        double a = 0.0;
        for (int d = 0; d < DIM; ++d)
            a = fma((double)cb0[i*DIM + d], (double)W_out[m*DIM + d], a);
        T0[tid] = (float)a;
    } else if (tid < 32768) {
        int t = tid - 16384;
        int i = t >> 7, m = t & 127;
        double a = 0.0;
        for (int d = 0; d < DIM; ++d)
            a = fma((double)cb1[i*DIM + d], (double)W_out[m*DIM + d], a);
        T1[t] = (float)a;
    } else if (tid < 40960) {               // WT[j][d] = W_in[d][j]
        int t = tid - 32768;
        int j = t >> 6, d = t & 63;
        WT[t] = W_in[d*MEL_BINS + j];
    } else if (tid < 41216) {
        int t = tid - 40960;
        const float* cb = (t & 128) ? cb1 : cb0;
        float*       nn = (t & 128) ? n1  : n0;
        int k = t & 127;
        nn[k] = np_pairwise64_sq(cb + k*DIM);
    } else if (tid < 49408) {               // c0T[d][k] = cb0[k][d]
        int t = tid - 41216;
        int d = t >> 7, k = t & 127;
        c0T[t] = cb0[k*DIM + d];
    } else if (tid < 57600) {
        int t = tid - 49408;
        int d = t >> 7, k = t & 127;
        c1T[t] = cb1[k*DIM + d];
    }
}

// One row/thread. z computed in two 32-d register halves (keeps VGPRs low),
// parked in padded LDS; dot loops roll over d reading z from LDS, 16 packed
// k-chains per chunk via v_pk_fma_f32. PER-VALUE FP ORDER IS BIT-IDENTICAL
// to the R3-verified np-f32 emulation — each z[d]/dot[k] chain is its own
// ascending single-accumulator fmaf chain; pairing is across independent
// values only. DO NOT REORDER.
__global__ __launch_bounds__(THREADS) void rvq_main(
    const float* __restrict__ mel,
    const float* __restrict__ b_in,
    const float* __restrict__ cb0,
    const float* __restrict__ cb1,
    const float* __restrict__ b_out,
    const float* __restrict__ ws,
    float* __restrict__ out_mel,
    float* __restrict__ out_idx)
{
#pragma clang fp contract(off)
    const v2f*   __restrict__ WTp = (const v2f*)(ws + WS_WT);
    const v2f*   __restrict__ c0P = (const v2f*)(ws + WS_C0T);
    const v2f*   __restrict__ c1P = (const v2f*)(ws + WS_C1T);
    const float* __restrict__ n0  = ws + WS_N0;
    const float* __restrict__ n1  = ws + WS_N1;
    const float* __restrict__ T0  = ws + WS_T0;
    const float* __restrict__ T1  = ws + WS_T1;
    const v2f*   __restrict__ bi2 = (const v2f*)b_in;

    __shared__ float zbuf[THREADS * 65];    // stride 65: (lane+d)%32 banks

    const int tid = threadIdx.x;
    const size_t b = (size_t)blockIdx.x * THREADS + tid;
    const int lb = tid * 65;

    const v4f* melp = (const v4f*)(mel + b * MEL_BINS);

    float r[8];                             // np pairwise accumulators (carried)
#pragma unroll
    for (int t = 0; t < 8; ++t) r[t] = 0.f;

    // ======== z-GEMM in two halves of 32 d (16 v2f pairs each) ========
#pragma unroll
    for (int half = 0; half < 2; ++half) {
        const int pbase = half * 16;        // pair offset into the 32-pair row
        v2f zh[16];
#pragma unroll
        for (int p = 0; p < 16; ++p) zh[p] = (v2f){0.f, 0.f};

        for (int jc = 0; jc < 32; ++jc) {
            v4f m4 = melp[jc];
            v2f m0 = (v2f){m4.x, m4.x};
            v2f m1 = (v2f){m4.y, m4.y};
            v2f m2 = (v2f){m4.z, m4.z};
            v2f m3 = (v2f){m4.w, m4.w};
            const v2f* w0 = WTp + (jc*4 + 0)*32 + pbase;
            const v2f* w1 = WTp + (jc*4 + 1)*32 + pbase;
            const v2f* w2 = WTp + (jc*4 + 2)*32 + pbase;
            const v2f* w3 = WTp + (jc*4 + 3)*32 + pbase;
#pragma unroll
            for (int p = 0; p < 16; ++p) PK(zh[p], w0[p], m0);
#pragma unroll
            for (int p = 0; p < 16; ++p) PK(zh[p], w1[p], m1);
#pragma unroll
            for (int p = 0; p < 16; ++p) PK(zh[p], w2[p], m2);
#pragma unroll
            for (int p = 0; p < 16; ++p) PK(zh[p], w3[p], m3);
        }
        // bias (separate rounded adds), squares (np order), park in LDS
#pragma unroll
        for (int p = 0; p < 16; ++p) {
            v2f bb = bi2[pbase + p];
            float vx = zh[p].x + bb.x;
            float vy = zh[p].y + bb.y;
            int d = half*32 + 2*p;
            r[d & 7]       += vx * vx;      // d ascending -> exact np order
            r[(d + 1) & 7] += vy * vy;
            zbuf[lb + d]     = vx;
            zbuf[lb + d + 1] = vy;
        }
        // prevent CSE of mel loads across halves (would hold 128 regs live)
        asm volatile("" : "+v"(melp));
    }
    float sum_rr = ((r[0] + r[1]) + (r[2] + r[3])) + ((r[4] + r[5]) + (r[6] + r[7]));

    // ======== codebook 0: 4 chunks x 32 k, 16 packed chains ========
    float best0 = 3.4e38f; int i0 = 0;
    for (int kc = 0; kc < 4; ++kc) {
        v2f a[16];
#pragma unroll
        for (int t = 0; t < 16; ++t) a[t] = (v2f){0.f, 0.f};
#pragma unroll 4
        for (int d = 0; d < DIM; ++d) {
            float zd = zbuf[lb + d];
            v2f zd2 = (v2f){zd, zd};
            const v2f* crow = c0P + d*64 + kc*16;   // uniform -> s_loads
#pragma unroll
            for (int t = 0; t < 16; ++t) PK(a[t], crow[t], zd2);
        }
#pragma unroll
        for (int t = 0; t < 16; ++t) {
            int k = kc*32 + 2*t;
            float d0 = (sum_rr - 2.0f*a[t].x) + n0[k];
            float d1 = (sum_rr - 2.0f*a[t].y) + n0[k+1];
            if (d0 < best0) { best0 = d0; i0 = k; }     // ascending k, strict <
            if (d1 < best0) { best0 = d1; i0 = k+1; }
        }
    }

    // ======== residual in LDS + fresh np pairwise squares ========
    {
        const float* c = cb0 + (size_t)i0 * DIM;        // per-lane gather
        float q[8];
#pragma unroll
        for (int t = 0; t < 8; ++t) q[t] = 0.f;
        for (int ib = 0; ib < 8; ++ib) {
            int d = ib * 8;
#pragma unroll
            for (int t = 0; t < 8; ++t) {
                float v = zbuf[lb + d + t] - c[d + t];  // rounded sub
                zbuf[lb + d + t] = v;
                q[t] += v * v;                          // i ascending per t
            }
        }
        sum_rr = ((q[0] + q[1]) + (q[2] + q[3])) + ((q[4] + q[5]) + (q[6] + q[7]));
    }

    // ======== codebook 1 ========
    float best1 = 3.4e38f; int i1 = 0;
    for (int kc = 0; kc < 4; ++kc) {
        v2f a[16];
#pragma unroll
        for (int t = 0; t < 16; ++t) a[t] = (v2f){0.f, 0.f};
#pragma unroll 4
        for (int d = 0; d < DIM; ++d) {
            float zd = zbuf[lb + d];
            v2f zd2 = (v2f){zd, zd};
            const v2f* crow = c1P + d*64 + kc*16;
#pragma unroll
            for (int t = 0; t < 16; ++t) PK(a[t], crow[t], zd2);
        }
#pragma unroll
        for (int t = 0; t < 16; ++t) {
            int k = kc*32 + 2*t;
            float d0 = (sum_rr - 2.0f*a[t].x) + n1[k];
            float d1 = (sum_rr - 2.0f*a[t].y) + n1[k+1];
            if (d0 < best1) { best1 = d0; i1 = k; }
            if (d1 < best1) { best1 = d1; i1 = k+1; }
        }
    }

    // ======== decode: out = T0[i0] + T1[i1] + b_out ========
    const v4f* t0r = (const v4f*)(T0 + (size_t)i0 * MEL_BINS);
    const v4f* t1r = (const v4f*)(T1 + (size_t)i1 * MEL_BINS);
    const v4f* bo  = (const v4f*)b_out;
    v4f* outr = (v4f*)(out_mel + b * MEL_BINS);
#pragma unroll 4
    for (int q = 0; q < MEL_BINS / 4; ++q) {
        v4f a = t0r[q], c = t1r[q], bb = bo[q];
        v4f o;
        o.x = a.x + c.x + bb.x;
        o.y = a.y + c.y + bb.y;
        o.z = a.z + c.z + bb.z;
        o.w = a.w + c.w + bb.w;
        outr[q] = o;
    }

    out_idx[2*b + 0] = (float)i0;
    out_idx[2*b + 1] = (float)i1;
}

extern "C" void kernel_launch(void* const* d_in, const int* in_sizes, int n_in,
                              void* d_out, int out_size, void* d_ws, size_t ws_size,
                              hipStream_t stream)
{
    const float* mel   = (const float*)d_in[0];
    const float* W_in  = (const float*)d_in[1];
    const float* b_in  = (const float*)d_in[2];
    const float* cb0   = (const float*)d_in[3];
    const float* cb1   = (const float*)d_in[4];
    const float* W_out = (const float*)d_in[5];
    const float* b_out = (const float*)d_in[6];

    float* ws      = (float*)d_ws;                 // 230400 bytes used
    float* out_mel = (float*)d_out;
    float* out_idx = (float*)d_out + (size_t)B_ROWS * MEL_BINS;

    rvq_precomp<<<(WS_TOT + 255) / 256, 256, 0, stream>>>(W_in, cb0, cb1, W_out, ws);
    rvq_main<<<B_ROWS / THREADS, THREADS, 0, stream>>>(mel, b_in, cb0, cb1, b_out,
                                                       ws, out_mel, out_idx);
}

// Round 9
// 659.207 us; speedup vs baseline: 1.6749x; 1.6749x over previous
//
#include <hip/hip_runtime.h>
#include <hip/hip_bf16.h>

#define B_ROWS   524288
#define MEL_BINS 128
#define DIM      64
#define KCODES   128
#define THREADS  128

// ---------------- workspace layout (floats) ----------------
// WT  [128*64]    : W_in^T, WT[j*64+d] = W_in[d*128+j]
// c0B [32*64*4]   : cb0 4-k panels, c0B[p*256 + d*4 + t] = cb0[(4p+t)*64 + d]
// c1B [32*64*4]   : cb1 panels
// n0,n1 [128]     : np pairwise ||c_k||^2
// T0,T1 [128*128] : cb @ W_out^T
#define WS_WT  0
#define WS_C0B (WS_WT + MEL_BINS*DIM)       // 8192
#define WS_C1B (WS_C0B + DIM*KCODES)        // 16384
#define WS_N0  (WS_C1B + DIM*KCODES)        // 24576
#define WS_N1  (WS_N0 + KCODES)             // 24704
#define WS_T0  (WS_N1 + KCODES)             // 24832
#define WS_T1  (WS_T0 + KCODES*MEL_BINS)    // 41216
#define WS_TOT (WS_T1 + KCODES*MEL_BINS)    // 57600 floats

// numpy pairwise_sum (scalar path) emulation for n=64 of v[d]*v[d].
__device__ __forceinline__ float np_pairwise64_sq(const float* v) {
#pragma clang fp contract(off)
    float r0 = v[0]*v[0], r1 = v[1]*v[1], r2 = v[2]*v[2], r3 = v[3]*v[3];
    float r4 = v[4]*v[4], r5 = v[5]*v[5], r6 = v[6]*v[6], r7 = v[7]*v[7];
#pragma unroll
    for (int i = 8; i < 64; i += 8) {
        r0 += v[i+0]*v[i+0]; r1 += v[i+1]*v[i+1];
        r2 += v[i+2]*v[i+2]; r3 += v[i+3]*v[i+3];
        r4 += v[i+4]*v[i+4]; r5 += v[i+5]*v[i+5];
        r6 += v[i+6]*v[i+6]; r7 += v[i+7]*v[i+7];
    }
    return ((r0 + r1) + (r2 + r3)) + ((r4 + r5) + (r6 + r7));
}

__global__ __launch_bounds__(256) void rvq_precomp(
    const float* __restrict__ W_in, const float* __restrict__ cb0,
    const float* __restrict__ cb1, const float* __restrict__ W_out,
    float* __restrict__ ws)
{
#pragma clang fp contract(off)
    float* WT  = ws + WS_WT;
    float* c0B = ws + WS_C0B;
    float* c1B = ws + WS_C1B;
    float* n0  = ws + WS_N0;
    float* n1  = ws + WS_N1;
    float* T0  = ws + WS_T0;
    float* T1  = ws + WS_T1;

    int tid = blockIdx.x * 256 + threadIdx.x;
    if (tid < 16384) {                       // T0[i][m] (mel path: loose threshold)
        int i = tid >> 7, m = tid & 127;
        double a = 0.0;
        for (int d = 0; d < DIM; ++d)
            a = fma((double)cb0[i*DIM + d], (double)W_out[m*DIM + d], a);
        T0[tid] = (float)a;
    } else if (tid < 32768) {                // T1[i][m]
        int t = tid - 16384;
        int i = t >> 7, m = t & 127;
        double a = 0.0;
        for (int d = 0; d < DIM; ++d)
            a = fma((double)cb1[i*DIM + d], (double)W_out[m*DIM + d], a);
        T1[t] = (float)a;
    } else if (tid < 40960) {                // WT[j][d] = W_in[d][j]
        int t = tid - 32768;
        int j = t >> 6, d = t & 63;
        WT[t] = W_in[d*MEL_BINS + j];
    } else if (tid < 41216) {                // n0 / n1 (exact np pairwise)
        int t = tid - 40960;
        const float* cb = (t & 128) ? cb1 : cb0;
        float*       nn = (t & 128) ? n1  : n0;
        int k = t & 127;
        nn[k] = np_pairwise64_sq(cb + k*DIM);
    } else if (tid < 49408) {                // c0B[p][d][t] = cb0[4p+t][d]
        int t = tid - 41216;
        int p = t >> 8, rem = t & 255;
        int d = rem >> 2, tt = rem & 3;
        c0B[t] = cb0[(4*p + tt)*DIM + d];
    } else if (tid < 57600) {                // c1B
        int t = tid - 49408;
        int p = t >> 8, rem = t & 255;
        int d = rem >> 2, tt = rem & 3;
        c1B[t] = cb1[(4*p + tt)*DIM + d];
    }
}

// 1 row/thread, 128-thread blocks. The 20480-B LDS array exists ONLY to cap
// occupancy at exactly 8 blocks/CU = 4 waves/SIMD: with that bound the
// register allocator budgets 128 arch VGPRs and keeps z[64] in VGPRs
// (no AGPR offload = the ~1.8x VALU inflation seen in R3-R6).
// Dot loops: 4-k panels, 4 independent ascending-d chains (ILP=4).
// PER-VALUE FP OP ORDER IS BIT-IDENTICAL to the R3-verified np-f32
// emulation — DO NOT REORDER.
__global__ __launch_bounds__(THREADS)
__attribute__((amdgpu_waves_per_eu(1, 4)))
void rvq_main(
    const float* __restrict__ mel,
    const float* __restrict__ b_in,
    const float* __restrict__ cb0,
    const float* __restrict__ cb1,
    const float* __restrict__ b_out,
    const float* __restrict__ ws,
    float* __restrict__ out_mel,
    float* __restrict__ out_idx)
{
#pragma clang fp contract(off)
    const float* __restrict__ WT  = ws + WS_WT;
    const float* __restrict__ c0B = ws + WS_C0B;
    const float* __restrict__ c1B = ws + WS_C1B;
    const float* __restrict__ n0  = ws + WS_N0;
    const float* __restrict__ n1  = ws + WS_N1;
    const float* __restrict__ T0  = ws + WS_T0;
    const float* __restrict__ T1  = ws + WS_T1;

    __shared__ float occ_cap[5120];          // 20480 B -> 8 blocks/CU cap

    const int b = blockIdx.x * THREADS + threadIdx.x;

    // ---- z = mel @ W_in^T : ascending-j fmaf chain per d (frozen order)
    float z[DIM];
#pragma unroll
    for (int d = 0; d < DIM; ++d) z[d] = 0.f;

    const float4* melr = reinterpret_cast<const float4*>(mel + (size_t)b * MEL_BINS);
    for (int jc = 0; jc < MEL_BINS / 4; ++jc) {
        float4 m4 = melr[jc];
        const float* w = WT + jc * 4 * DIM;   // wave-uniform -> scalar loads
#pragma unroll
        for (int d = 0; d < DIM; ++d) z[d] = fmaf(w[d],         m4.x, z[d]);
#pragma unroll
        for (int d = 0; d < DIM; ++d) z[d] = fmaf(w[DIM + d],   m4.y, z[d]);
#pragma unroll
        for (int d = 0; d < DIM; ++d) z[d] = fmaf(w[2*DIM + d], m4.z, z[d]);
#pragma unroll
        for (int d = 0; d < DIM; ++d) z[d] = fmaf(w[3*DIM + d], m4.w, z[d]);
    }
#pragma unroll
    for (int d = 0; d < DIM; ++d) z[d] = z[d] + b_in[d];

    // ================= codebook 0 =================
    float s0 = z[0]*z[0], s1 = z[1]*z[1], s2 = z[2]*z[2], s3 = z[3]*z[3];
    float s4 = z[4]*z[4], s5 = z[5]*z[5], s6 = z[6]*z[6], s7 = z[7]*z[7];
#pragma unroll
    for (int i = 8; i < 64; i += 8) {
        s0 += z[i+0]*z[i+0]; s1 += z[i+1]*z[i+1];
        s2 += z[i+2]*z[i+2]; s3 += z[i+3]*z[i+3];
        s4 += z[i+4]*z[i+4]; s5 += z[i+5]*z[i+5];
        s6 += z[i+6]*z[i+6]; s7 += z[i+7]*z[i+7];
    }
    float sum_rr = ((s0 + s1) + (s2 + s3)) + ((s4 + s5) + (s6 + s7));

    // keep occ_cap alive; branch never taken (b < B_ROWS) but unprovable
    if (b == 0x7FFFFFF0) {
        occ_cap[threadIdx.x] = sum_rr;
        __syncthreads();
        out_mel[0] = occ_cap[(threadIdx.x + 1) & 127];
    }

    float best0 = 3.4e38f; int i0 = 0;
    for (int p = 0; p < 32; ++p) {           // rolled: 4-k panel per iter
        const float* cp = c0B + p * 256;     // wave-uniform -> s_load stream
        float a0 = 0.f, a1 = 0.f, a2 = 0.f, a3 = 0.f;
#pragma unroll
        for (int d = 0; d < DIM; ++d) {      // 4 independent ascending-d chains
            float zd = z[d];
            a0 = fmaf(cp[d*4 + 0], zd, a0);
            a1 = fmaf(cp[d*4 + 1], zd, a1);
            a2 = fmaf(cp[d*4 + 2], zd, a2);
            a3 = fmaf(cp[d*4 + 3], zd, a3);
        }
        int k = p * 4;
        float d0 = (sum_rr - 2.0f*a0) + n0[k + 0];
        float d1 = (sum_rr - 2.0f*a1) + n0[k + 1];
        float d2 = (sum_rr - 2.0f*a2) + n0[k + 2];
        float d3 = (sum_rr - 2.0f*a3) + n0[k + 3];
        if (d0 < best0) { best0 = d0; i0 = k + 0; }   // ascending k, strict <
        if (d1 < best0) { best0 = d1; i0 = k + 1; }
        if (d2 < best0) { best0 = d2; i0 = k + 2; }
        if (d3 < best0) { best0 = d3; i0 = k + 3; }
    }

    // residual = r - code : elementwise rounded sub (per-lane gather)
    {
        const float* c = cb0 + (size_t)i0 * DIM;
#pragma unroll
        for (int d = 0; d < DIM; ++d) z[d] = z[d] - c[d];
    }

    // ================= codebook 1 =================
    s0 = z[0]*z[0]; s1 = z[1]*z[1]; s2 = z[2]*z[2]; s3 = z[3]*z[3];
    s4 = z[4]*z[4]; s5 = z[5]*z[5]; s6 = z[6]*z[6]; s7 = z[7]*z[7];
#pragma unroll
    for (int i = 8; i < 64; i += 8) {
        s0 += z[i+0]*z[i+0]; s1 += z[i+1]*z[i+1];
        s2 += z[i+2]*z[i+2]; s3 += z[i+3]*z[i+3];
        s4 += z[i+4]*z[i+4]; s5 += z[i+5]*z[i+5];
        s6 += z[i+6]*z[i+6]; s7 += z[i+7]*z[i+7];
    }
    sum_rr = ((s0 + s1) + (s2 + s3)) + ((s4 + s5) + (s6 + s7));

    float best1 = 3.4e38f; int i1 = 0;
    for (int p = 0; p < 32; ++p) {
        const float* cp = c1B + p * 256;
        float a0 = 0.f, a1 = 0.f, a2 = 0.f, a3 = 0.f;
#pragma unroll
        for (int d = 0; d < DIM; ++d) {
            float zd = z[d];
            a0 = fmaf(cp[d*4 + 0], zd, a0);
            a1 = fmaf(cp[d*4 + 1], zd, a1);
            a2 = fmaf(cp[d*4 + 2], zd, a2);
            a3 = fmaf(cp[d*4 + 3], zd, a3);
        }
        int k = p * 4;
        float d0 = (sum_rr - 2.0f*a0) + n1[k + 0];
        float d1 = (sum_rr - 2.0f*a1) + n1[k + 1];
        float d2 = (sum_rr - 2.0f*a2) + n1[k + 2];
        float d3 = (sum_rr - 2.0f*a3) + n1[k + 3];
        if (d0 < best1) { best1 = d0; i1 = k + 0; }
        if (d1 < best1) { best1 = d1; i1 = k + 1; }
        if (d2 < best1) { best1 = d2; i1 = k + 2; }
        if (d3 < best1) { best1 = d3; i1 = k + 3; }
    }

    // ---- decode: out = T0[i0] + T1[i1] + b_out
    const float4* t0r = reinterpret_cast<const float4*>(T0 + (size_t)i0 * MEL_BINS);
    const float4* t1r = reinterpret_cast<const float4*>(T1 + (size_t)i1 * MEL_BINS);
    float4* outr = reinterpret_cast<float4*>(out_mel + (size_t)b * MEL_BINS);
#pragma unroll 4
    for (int q = 0; q < MEL_BINS / 4; ++q) {
        float4 a = t0r[q], c = t1r[q];
        float4 o;
        o.x = a.x + c.x + b_out[4*q + 0];
        o.y = a.y + c.y + b_out[4*q + 1];
        o.z = a.z + c.z + b_out[4*q + 2];
        o.w = a.w + c.w + b_out[4*q + 3];
        outr[q] = o;
    }

    out_idx[2*(size_t)b + 0] = (float)i0;
    out_idx[2*(size_t)b + 1] = (float)i1;
}

extern "C" void kernel_launch(void* const* d_in, const int* in_sizes, int n_in,
                              void* d_out, int out_size, void* d_ws, size_t ws_size,
                              hipStream_t stream)
{
    const float* mel   = (const float*)d_in[0];
    const float* W_in  = (const float*)d_in[1];
    const float* b_in  = (const float*)d_in[2];
    const float* cb0   = (const float*)d_in[3];
    const float* cb1   = (const float*)d_in[4];
    const float* W_out = (const float*)d_in[5];
    const float* b_out = (const float*)d_in[6];

    float* ws      = (float*)d_ws;                 // 230400 bytes used
    float* out_mel = (float*)d_out;
    float* out_idx = (float*)d_out + (size_t)B_ROWS * MEL_BINS;

    rvq_precomp<<<(WS_TOT + 255) / 256, 256, 0, stream>>>(W_in, cb0, cb1, W_out, ws);
    rvq_main<<<B_ROWS / THREADS, THREADS, 0, stream>>>(mel, b_in, cb0, cb1, b_out,
                                                       ws, out_mel, out_idx);
}